// Round 6
// baseline (254.032 us; speedup 1.0000x reference)
//
#include <hip/hip_runtime.h>
#include <hip/hip_bf16.h>

// Problem constants (b=2, l=4, n=1024, dim=512, heads=8, dh=64, nsample=8)
// All d_in / d_out buffers are FLOAT32 (reference dtypes). Internal compute
// uses bf16 MFMA (allowed by the bf16-mode absmax threshold 0.105).
#define B_ 2
#define L_ 4
#define N_ 1024
#define DIM_ 512
#define INNER_ 512
#define HEADS_ 8
#define DH_ 64
#define NS_ 8
#define NFR_ (B_ * L_)            // 8 flat frames
#define ROWS_ (B_ * L_ * N_)      // 8192 point rows

typedef unsigned short u16;
typedef __attribute__((ext_vector_type(8))) short bf16x8;
typedef __attribute__((ext_vector_type(4))) float f32x4;

__device__ inline float bf2f(u16 u) {
    union { unsigned i; float f; } c; c.i = ((unsigned)u) << 16; return c.f;
}
__device__ inline u16 f2bf(float x) {
    __hip_bfloat16 h = __float2bfloat16(x);  // round-to-nearest-even
    return *reinterpret_cast<u16*>(&h);
}

// 8-element bf16 dot with f32 accumulate; v_dot2_f32_bf16 when available.
#if __has_builtin(__builtin_amdgcn_fdot2_f32_bf16)
typedef __bf16 bf2v __attribute__((ext_vector_type(2)));
__device__ inline float dot8(bf16x8 a, bf16x8 b, float acc) {
    union U { bf16x8 v; bf2v p[4]; };
    U ua, ub; ua.v = a; ub.v = b;
    #pragma unroll
    for (int i = 0; i < 4; ++i)
        acc = __builtin_amdgcn_fdot2_f32_bf16(ua.p[i], ub.p[i], acc, false);
    return acc;
}
#else
__device__ inline float dot8(bf16x8 a, bf16x8 b, float acc) {
    #pragma unroll
    for (int e = 0; e < 8; ++e) acc += bf2f((u16)a[e]) * bf2f((u16)b[e]);
    return acc;
}
#endif

// ---------------------------------------------------------------------------
// K0: transpose + bf16-cast w_qkv (512x1536 -> 1536x512) and w_out (512x512)
// ---------------------------------------------------------------------------
__global__ __launch_bounds__(256) void transpose_w(
    const float* __restrict__ wqkv, const float* __restrict__ wout,
    u16* __restrict__ wqkvT, u16* __restrict__ woutT)
{
    int i = blockIdx.x * 256 + threadIdx.x;
    const int T1 = DIM_ * 3 * INNER_;          // 786432
    if (i < T1) {
        int k = i / (3 * INNER_);
        int c = i - k * (3 * INNER_);
        wqkvT[c * DIM_ + k] = f2bf(wqkv[i]);
    } else {
        int i2 = i - T1;
        if (i2 < INNER_ * DIM_) {
            int k = i2 >> 9;                   // /512
            int c = i2 & 511;
            woutT[c * INNER_ + k] = f2bf(wout[i2]);
        }
    }
}

// ---------------------------------------------------------------------------
// K1: LayerNorm over channel dim (512) -> bf16 normf.  One block per row.
// ---------------------------------------------------------------------------
__global__ __launch_bounds__(256) void ln_kernel(
    const float* __restrict__ f, const float* __restrict__ g,
    const float* __restrict__ b, u16* __restrict__ o)
{
    int row = blockIdx.x;
    int t = threadIdx.x;
    const float* fr = f + (size_t)row * DIM_;
    float x0 = fr[t], x1 = fr[t + 256];

    __shared__ float red[4];
    float s = x0 + x1;
    #pragma unroll
    for (int off = 32; off; off >>= 1) s += __shfl_xor(s, off, 64);
    if ((t & 63) == 0) red[t >> 6] = s;
    __syncthreads();
    float mu = (red[0] + red[1] + red[2] + red[3]) * (1.0f / 512.0f);
    __syncthreads();

    float d0 = x0 - mu, d1 = x1 - mu;
    float q = d0 * d0 + d1 * d1;
    #pragma unroll
    for (int off = 32; off; off >>= 1) q += __shfl_xor(q, off, 64);
    if ((t & 63) == 0) red[t >> 6] = q;
    __syncthreads();
    float var = (red[0] + red[1] + red[2] + red[3]) * (1.0f / 512.0f);
    float inv = rsqrtf(var + 1e-5f);

    o[(size_t)row * DIM_ + t]       = f2bf(d0 * inv * g[t]       + b[t]);
    o[(size_t)row * DIM_ + t + 256] = f2bf(d1 * inv * g[t + 256] + b[t + 256]);
}

// ---------------------------------------------------------------------------
// K2/K5: MFMA bf16 GEMM, C[M,N] = A[M,K] @ Bt[N,K]^T.
// 128x128 block tile, BK=32, 256 threads (4 waves, each 64x64).
// mode 0: Cb16 = bf16(acc)                          (qkv, bf16 ws)
// mode 1: Cf32 = gelu(acc + bias) + resid           (final output, f32)
// ---------------------------------------------------------------------------
__global__ __launch_bounds__(256) void gemm_bt(
    const u16* __restrict__ A, const u16* __restrict__ Bt,
    u16* __restrict__ Cb16, float* __restrict__ Cf32,
    int M, int N, int K, int nb128, int mode,
    const float* __restrict__ bias, const float* __restrict__ resid)
{
    __shared__ u16 As[128 * 40];   // stride 40 bf16 = 80B (16B aligned)
    __shared__ u16 Bs[128 * 40];

    int bx = blockIdx.x % nb128;
    int by = blockIdx.x / nb128;
    int m0 = by * 128, n0 = bx * 128;
    int t = threadIdx.x;
    int wave = t >> 6, lane = t & 63;
    int lr = lane & 15, quad = lane >> 4;
    int wm = (wave >> 1) * 64, wn = (wave & 1) * 64;

    f32x4 acc[4][4];
    #pragma unroll
    for (int i = 0; i < 4; ++i)
        #pragma unroll
        for (int j = 0; j < 4; ++j)
            acc[i][j] = {0.f, 0.f, 0.f, 0.f};

    for (int k0 = 0; k0 < K; k0 += 32) {
        #pragma unroll
        for (int p = 0; p < 2; ++p) {
            int c = t + p * 256;           // 0..511
            int r = c >> 2;                // 0..127
            int kc = (c & 3) * 8;          // 0,8,16,24
            *(bf16x8*)&As[r * 40 + kc] = *(const bf16x8*)(A + (size_t)(m0 + r) * K + k0 + kc);
            *(bf16x8*)&Bs[r * 40 + kc] = *(const bf16x8*)(Bt + (size_t)(n0 + r) * K + k0 + kc);
        }
        __syncthreads();

        bf16x8 af[4], bfr[4];
        #pragma unroll
        for (int mb = 0; mb < 4; ++mb)
            af[mb] = *(const bf16x8*)&As[(wm + mb * 16 + lr) * 40 + quad * 8];
        #pragma unroll
        for (int nb = 0; nb < 4; ++nb)
            bfr[nb] = *(const bf16x8*)&Bs[(wn + nb * 16 + lr) * 40 + quad * 8];
        #pragma unroll
        for (int mb = 0; mb < 4; ++mb)
            #pragma unroll
            for (int nb = 0; nb < 4; ++nb)
                acc[mb][nb] = __builtin_amdgcn_mfma_f32_16x16x32_bf16(
                    af[mb], bfr[nb], acc[mb][nb], 0, 0, 0);
        __syncthreads();
    }

    #pragma unroll
    for (int mb = 0; mb < 4; ++mb) {
        #pragma unroll
        for (int nb = 0; nb < 4; ++nb) {
            int col = n0 + wn + nb * 16 + lr;
            #pragma unroll
            for (int r = 0; r < 4; ++r) {
                int row = m0 + wm + mb * 16 + quad * 4 + r;
                float x = acc[mb][nb][r];
                if (mode == 1) {
                    x += bias[col];
                    float gl = 0.5f * x * (1.0f + erff(x * 0.70710678118654752f));
                    Cf32[(size_t)row * N + col] = gl + resid[(size_t)row * N + col];
                } else {
                    Cb16[(size_t)row * N + col] = f2bf(x);
                }
            }
        }
    }
}

// ---------------------------------------------------------------------------
// K3: ball query, wave-parallel. One wave per query; 64 lanes each test a
// contiguous 16-point chunk (lane order = index order), so prefix-sum of
// per-lane popcounts assigns the first-8-lowest-index output slots exactly
// like the sequential scan. Block = 4 waves = 4 queries sharing one
// LDS-staged ref frame.
// LDS pad: R(r)=r+(r>>4) -> read addr = lane*17+j; 17 coprime 32 => every
// bank hit by exactly 2 lanes (free). d2 math identical to ref (contract off).
// idxt layout: [(qi*2+bi)*1024+n][jf*8+s]  (32 consecutive ints per query)
// ---------------------------------------------------------------------------
#define RPAD_(r) ((r) + ((r) >> 4))

__global__ __launch_bounds__(256) void ballq_kernel(
    const float* __restrict__ xyz, int* __restrict__ idxt)
{
    #pragma clang fp contract(off)
    int blk = blockIdx.x;               // 8192 blocks: combo*256 + qgroup
    int qgroup = blk & 255;
    int combo = blk >> 8;               // qi*8 + bi*4 + jf
    int jf = combo & 3;
    int bi = (combo >> 2) & 1;
    int qi = combo >> 3;

    __shared__ float rx[N_ + (N_ >> 4)], ry[N_ + (N_ >> 4)], rz[N_ + (N_ >> 4)];
    const float* ref = xyz + (size_t)((bi * L_ + jf) * N_) * 3;
    for (int p = threadIdx.x; p < N_; p += 256) {
        rx[RPAD_(p)] = ref[p * 3 + 0];
        ry[RPAD_(p)] = ref[p * 3 + 1];
        rz[RPAD_(p)] = ref[p * 3 + 2];
    }
    __syncthreads();

    int wave = threadIdx.x >> 6;
    int lane = threadIdx.x & 63;
    int n = qgroup * 4 + wave;

    const float* qp = xyz + (size_t)((bi * L_ + qi) * N_ + n) * 3;
    float qx = qp[0], qy = qp[1], qz = qp[2];

    int base = lane * 17;               // RPAD_(lane*16)
    unsigned mask = 0;
    #pragma unroll
    for (int j = 0; j < 16; ++j) {
        float dx = qx - rx[base + j];
        float dy = qy - ry[base + j];
        float dz = qz - rz[base + j];
        float d2 = dx * dx + dy * dy;
        d2 = d2 + dz * dz;
        if (d2 < 0.04f) mask |= (1u << j);
    }

    int cnt = __popc(mask);
    int x = cnt;
    #pragma unroll
    for (int off = 1; off < 64; off <<= 1) {
        int y = __shfl_up(x, off, 64);
        if (lane >= off) x += y;
    }
    int pre = x - cnt;                       // exclusive prefix
    int total = __shfl(x, 63, 64);           // total in-radius count

    int r0 = lane * 16;
    int localFirst = mask ? (r0 + __builtin_ctz(mask)) : 0x7fffffff;
    int gfirst = localFirst;
    #pragma unroll
    for (int off = 32; off; off >>= 1) gfirst = min(gfirst, __shfl_xor(gfirst, off, 64));

    int* o = idxt + ((size_t)((qi * B_ + bi) * N_ + n)) * 32 + jf * NS_;

    unsigned m = mask;
    int pos = pre;
    while (m && pos < NS_) {
        int j = __builtin_ctz(m);
        o[pos] = r0 + j;
        m &= m - 1;
        ++pos;
    }
    if (lane == 0) {
        int padv = (total > 0) ? gfirst : 0;
        for (int s = (total < NS_ ? total : NS_); s < NS_; ++s) o[s] = padv;
    }
}

// ---------------------------------------------------------------------------
// K4: attention v3 — ONE WAVE PER QUERY.  Block = 256 thr = 4 waves =
// 4 independent queries (no cross-wave data flow; LDS sliced per wave).
// Lane = (head h = lane>>3, sample s = lane&7).
// Phase A: 4 in-lane 64-dim QK dots (one per ref frame, v_dot2_f32_bf16),
//          softmax + attn*disp max reduced over the 8-lane head group.
// Phase C: lane owns 8 output dims of head h; PV over 32 neighbors with
//          16B V loads; spatial projection fused; 16B coalesced store.
// ---------------------------------------------------------------------------
__global__ __launch_bounds__(256) void attn_kernel(
    const float* __restrict__ xyz, const u16* __restrict__ qkv,
    const int* __restrict__ idxt, const float* __restrict__ wsp,
    u16* __restrict__ fres)
{
    int wq = threadIdx.x >> 6;
    int q = blockIdx.x * 4 + wq;        // (qi*2 + bi)*1024 + n
    int lane = threadIdx.x & 63;
    int h = lane >> 3;
    int s = lane & 7;

    int n = q & 1023;
    int bc = q >> 10;
    int bi = bc & 1;
    int qi = bc >> 1;
    int qrow = (bi * L_ + qi) * N_ + n;                  // xyz/qkv row
    int qq = (qi * B_ + bi) * N_ + n;                    // idxt row

    __shared__ float a_s[4][HEADS_][32];
    __shared__ int grow_s[4][32];
    __shared__ float da_s[4][HEADS_][3];

    // --- Phase A: 4 logits per lane (frames jf=0..3, sample s, head h) ---
    const u16* qp = qkv + (size_t)qrow * 1536 + h * 64;
    bf16x8 qv[8];
    #pragma unroll
    for (int c = 0; c < 8; ++c) qv[c] = *(const bf16x8*)(qp + c * 8);

    int kr[4];
    float lg[4];
    #pragma unroll
    for (int jf = 0; jf < 4; ++jf) {
        int idx = idxt[(size_t)qq * 32 + jf * 8 + s];
        kr[jf] = (bi * L_ + jf) * N_ + idx;
        const u16* kp = qkv + (size_t)kr[jf] * 1536 + 512 + h * 64;
        float acc = 0.f;
        #pragma unroll
        for (int c = 0; c < 8; ++c)
            acc = dot8(*(const bf16x8*)(kp + c * 8), qv[c], acc);
        lg[jf] = acc * 0.125f;           // scale = dh^-0.5
    }

    // --- softmax over head group (8 lanes x 4 regs = 32 logits) ---
    float mx = fmaxf(fmaxf(lg[0], lg[1]), fmaxf(lg[2], lg[3]));
    #pragma unroll
    for (int off = 1; off < 8; off <<= 1) mx = fmaxf(mx, __shfl_xor(mx, off, 64));
    float a[4], sum = 0.f;
    #pragma unroll
    for (int jf = 0; jf < 4; ++jf) { a[jf] = expf(lg[jf] - mx); sum += a[jf]; }
    #pragma unroll
    for (int off = 1; off < 8; off <<= 1) sum += __shfl_xor(sum, off, 64);
    float inv = 1.0f / sum;
    #pragma unroll
    for (int jf = 0; jf < 4; ++jf) {
        a[jf] *= inv;
        a_s[wq][h][jf * 8 + s] = a[jf];
    }
    if (h == 0) {
        #pragma unroll
        for (int jf = 0; jf < 4; ++jf) grow_s[wq][jf * 8 + s] = kr[jf];
    }

    // --- attn * disp max over the head group ---
    float qx = xyz[(size_t)qrow * 3 + 0];
    float qy = xyz[(size_t)qrow * 3 + 1];
    float qz = xyz[(size_t)qrow * 3 + 2];
    float tx, ty, tz;
    #pragma unroll
    for (int jf = 0; jf < 4; ++jf) {
        float gx = a[jf] * (xyz[(size_t)kr[jf] * 3 + 0] - qx);
        float gy = a[jf] * (xyz[(size_t)kr[jf] * 3 + 1] - qy);
        float gz = a[jf] * (xyz[(size_t)kr[jf] * 3 + 2] - qz);
        if (jf == 0) { tx = gx; ty = gy; tz = gz; }
        else { tx = fmaxf(tx, gx); ty = fmaxf(ty, gy); tz = fmaxf(tz, gz); }
    }
    #pragma unroll
    for (int off = 1; off < 8; off <<= 1) {
        tx = fmaxf(tx, __shfl_xor(tx, off, 64));
        ty = fmaxf(ty, __shfl_xor(ty, off, 64));
        tz = fmaxf(tz, __shfl_xor(tz, off, 64));
    }
    if (s == 0) { da_s[wq][h][0] = tx; da_s[wq][h][1] = ty; da_s[wq][h][2] = tz; }

    __syncthreads();   // cheap safety barrier (waves are symmetric)

    // --- Phase C: PV + spatial projection.  lane -> (h, 8 dims s*8..s*8+7) ---
    int d0 = s * 8;
    const u16* vbase = qkv + 1024 + h * 64 + d0;
    float o[8];
    #pragma unroll
    for (int e = 0; e < 8; ++e) o[e] = 0.f;
    #pragma unroll
    for (int t = 0; t < 32; ++t) {
        int krt = grow_s[wq][t];
        float at = a_s[wq][h][t];
        bf16x8 vv = *(const bf16x8*)(vbase + (size_t)krt * 1536);
        #pragma unroll
        for (int e = 0; e < 8; ++e) o[e] += at * bf2f((u16)vv[e]);
    }
    float dax = da_s[wq][h][0], day = da_s[wq][h][1], daz = da_s[wq][h][2];
    u16 outw[8];
    #pragma unroll
    for (int e = 0; e < 8; ++e) {
        float sp = dax * wsp[d0 + e] + day * wsp[64 + d0 + e] + daz * wsp[128 + d0 + e];
        outw[e] = f2bf(o[e] + sp);
    }
    *(bf16x8*)(fres + (size_t)qrow * INNER_ + h * 64 + d0) = *(bf16x8*)outw;
}

// ---------------------------------------------------------------------------
extern "C" void kernel_launch(void* const* d_in, const int* in_sizes, int n_in,
                              void* d_out, int out_size, void* d_ws, size_t ws_size,
                              hipStream_t stream) {
    const float* xyz   = (const float*)d_in[0];   // (2,4,1024,3)
    const float* feat  = (const float*)d_in[1];   // (2,4,1024,512)
    const float* gamma = (const float*)d_in[2];   // (512)
    const float* beta  = (const float*)d_in[3];   // (512)
    const float* wqkv  = (const float*)d_in[4];   // (512,1536)
    const float* wsp   = (const float*)d_in[5];   // (3,64)
    const float* wout  = (const float*)d_in[6];   // (512,512)
    const float* bout  = (const float*)d_in[7];   // (512)
    float* out = (float*)d_out;

    char* ws = (char*)d_ws;
    u16* normf = (u16*)ws;                 ws += (size_t)ROWS_ * DIM_ * 2;        // 8 MB
    u16* wqkvT = (u16*)ws;                 ws += (size_t)3 * INNER_ * DIM_ * 2;   // 1.5 MB
    u16* woutT = (u16*)ws;                 ws += (size_t)DIM_ * INNER_ * 2;       // 0.5 MB
    u16* qkv   = (u16*)ws;                 ws += (size_t)ROWS_ * 3 * INNER_ * 2;  // 24 MB
    int* idxt  = (int*)ws;                 ws += (size_t)L_ * NFR_ * N_ * NS_ * 4;// 1 MB
    u16* fres  = normf;   // alias: normf is dead after GEMM1 completes

    transpose_w<<<4096, 256, 0, stream>>>(wqkv, wout, wqkvT, woutT);
    ln_kernel<<<ROWS_, 256, 0, stream>>>(feat, gamma, beta, normf);
    // qkv = normf @ w_qkv : M=8192, N=1536, K=512
    gemm_bt<<<64 * 12, 256, 0, stream>>>(normf, wqkvT, qkv, nullptr,
                                         ROWS_, 3 * INNER_, DIM_, 12, 0, nullptr, nullptr);
    ballq_kernel<<<32 * 256, 256, 0, stream>>>(xyz, idxt);
    attn_kernel<<<ROWS_ / 4, 256, 0, stream>>>(xyz, qkv, idxt, wsp, fres);
    // out = gelu(fres @ w_out + b_out) + feature : M=8192, N=512, K=512
    gemm_bt<<<64 * 4, 256, 0, stream>>>(fres, woutT, nullptr, out,
                                        ROWS_, DIM_, INNER_, 4, 1, bout, feat);
}

// Round 7
// 237.096 us; speedup vs baseline: 1.0714x; 1.0714x over previous
//
#include <hip/hip_runtime.h>
#include <hip/hip_bf16.h>

// Problem constants (b=2, l=4, n=1024, dim=512, heads=8, dh=64, nsample=8)
// All d_in / d_out buffers are FLOAT32 (reference dtypes). Internal compute
// uses bf16 MFMA (allowed by the bf16-mode absmax threshold 0.105).
#define B_ 2
#define L_ 4
#define N_ 1024
#define DIM_ 512
#define INNER_ 512
#define HEADS_ 8
#define DH_ 64
#define NS_ 8
#define NFR_ (B_ * L_)            // 8 flat frames
#define ROWS_ (B_ * L_ * N_)      // 8192 point rows

typedef unsigned short u16;
typedef __attribute__((ext_vector_type(8))) short bf16x8;
typedef __attribute__((ext_vector_type(4))) float f32x4;

__device__ inline float bf2f(u16 u) {
    union { unsigned i; float f; } c; c.i = ((unsigned)u) << 16; return c.f;
}
__device__ inline float bflo(unsigned v) {   // low bf16 of dword -> f32
    union { unsigned i; float f; } c; c.i = v << 16; return c.f;
}
__device__ inline float bfhi(unsigned v) {   // high bf16 of dword -> f32
    union { unsigned i; float f; } c; c.i = v & 0xffff0000u; return c.f;
}
__device__ inline u16 f2bf(float x) {
    __hip_bfloat16 h = __float2bfloat16(x);  // round-to-nearest-even
    return *reinterpret_cast<u16*>(&h);
}

// 8-element bf16 dot with f32 accumulate; v_dot2_f32_bf16 when available.
#if __has_builtin(__builtin_amdgcn_fdot2_f32_bf16)
typedef __bf16 bf2v __attribute__((ext_vector_type(2)));
__device__ inline float dot8(bf16x8 a, bf16x8 b, float acc) {
    union U { bf16x8 v; bf2v p[4]; };
    U ua, ub; ua.v = a; ub.v = b;
    #pragma unroll
    for (int i = 0; i < 4; ++i)
        acc = __builtin_amdgcn_fdot2_f32_bf16(ua.p[i], ub.p[i], acc, false);
    return acc;
}
#else
__device__ inline float dot8(bf16x8 a, bf16x8 b, float acc) {
    #pragma unroll
    for (int e = 0; e < 8; ++e) acc += bf2f((u16)a[e]) * bf2f((u16)b[e]);
    return acc;
}
#endif

// ---------------------------------------------------------------------------
// K0: transpose + bf16-cast w_qkv (512x1536 -> 1536x512) and w_out (512x512)
// ---------------------------------------------------------------------------
__global__ __launch_bounds__(256) void transpose_w(
    const float* __restrict__ wqkv, const float* __restrict__ wout,
    u16* __restrict__ wqkvT, u16* __restrict__ woutT)
{
    int i = blockIdx.x * 256 + threadIdx.x;
    const int T1 = DIM_ * 3 * INNER_;          // 786432
    if (i < T1) {
        int k = i / (3 * INNER_);
        int c = i - k * (3 * INNER_);
        wqkvT[c * DIM_ + k] = f2bf(wqkv[i]);
    } else {
        int i2 = i - T1;
        if (i2 < INNER_ * DIM_) {
            int k = i2 >> 9;                   // /512
            int c = i2 & 511;
            woutT[c * INNER_ + k] = f2bf(wout[i2]);
        }
    }
}

// ---------------------------------------------------------------------------
// K1: LayerNorm over channel dim (512) -> bf16 normf.  One block per row.
// ---------------------------------------------------------------------------
__global__ __launch_bounds__(256) void ln_kernel(
    const float* __restrict__ f, const float* __restrict__ g,
    const float* __restrict__ b, u16* __restrict__ o)
{
    int row = blockIdx.x;
    int t = threadIdx.x;
    const float* fr = f + (size_t)row * DIM_;
    float x0 = fr[t], x1 = fr[t + 256];

    __shared__ float red[4];
    float s = x0 + x1;
    #pragma unroll
    for (int off = 32; off; off >>= 1) s += __shfl_xor(s, off, 64);
    if ((t & 63) == 0) red[t >> 6] = s;
    __syncthreads();
    float mu = (red[0] + red[1] + red[2] + red[3]) * (1.0f / 512.0f);
    __syncthreads();

    float d0 = x0 - mu, d1 = x1 - mu;
    float q = d0 * d0 + d1 * d1;
    #pragma unroll
    for (int off = 32; off; off >>= 1) q += __shfl_xor(q, off, 64);
    if ((t & 63) == 0) red[t >> 6] = q;
    __syncthreads();
    float var = (red[0] + red[1] + red[2] + red[3]) * (1.0f / 512.0f);
    float inv = rsqrtf(var + 1e-5f);

    o[(size_t)row * DIM_ + t]       = f2bf(d0 * inv * g[t]       + b[t]);
    o[(size_t)row * DIM_ + t + 256] = f2bf(d1 * inv * g[t + 256] + b[t + 256]);
}

// ---------------------------------------------------------------------------
// K2/K5: MFMA bf16 GEMM, C[M,N] = A[M,K] @ Bt[N,K]^T.
// 128x128 block tile, BK=32, 256 threads (4 waves, each 64x64).
// mode 0: Cb16 = bf16(acc)                          (qkv, bf16 ws)
// mode 1: Cf32 = gelu(acc + bias) + resid           (final output, f32)
// ---------------------------------------------------------------------------
__global__ __launch_bounds__(256) void gemm_bt(
    const u16* __restrict__ A, const u16* __restrict__ Bt,
    u16* __restrict__ Cb16, float* __restrict__ Cf32,
    int M, int N, int K, int nb128, int mode,
    const float* __restrict__ bias, const float* __restrict__ resid)
{
    __shared__ u16 As[128 * 40];   // stride 40 bf16 = 80B (16B aligned)
    __shared__ u16 Bs[128 * 40];

    int bx = blockIdx.x % nb128;
    int by = blockIdx.x / nb128;
    int m0 = by * 128, n0 = bx * 128;
    int t = threadIdx.x;
    int wave = t >> 6, lane = t & 63;
    int lr = lane & 15, quad = lane >> 4;
    int wm = (wave >> 1) * 64, wn = (wave & 1) * 64;

    f32x4 acc[4][4];
    #pragma unroll
    for (int i = 0; i < 4; ++i)
        #pragma unroll
        for (int j = 0; j < 4; ++j)
            acc[i][j] = {0.f, 0.f, 0.f, 0.f};

    for (int k0 = 0; k0 < K; k0 += 32) {
        #pragma unroll
        for (int p = 0; p < 2; ++p) {
            int c = t + p * 256;           // 0..511
            int r = c >> 2;                // 0..127
            int kc = (c & 3) * 8;          // 0,8,16,24
            *(bf16x8*)&As[r * 40 + kc] = *(const bf16x8*)(A + (size_t)(m0 + r) * K + k0 + kc);
            *(bf16x8*)&Bs[r * 40 + kc] = *(const bf16x8*)(Bt + (size_t)(n0 + r) * K + k0 + kc);
        }
        __syncthreads();

        bf16x8 af[4], bfr[4];
        #pragma unroll
        for (int mb = 0; mb < 4; ++mb)
            af[mb] = *(const bf16x8*)&As[(wm + mb * 16 + lr) * 40 + quad * 8];
        #pragma unroll
        for (int nb = 0; nb < 4; ++nb)
            bfr[nb] = *(const bf16x8*)&Bs[(wn + nb * 16 + lr) * 40 + quad * 8];
        #pragma unroll
        for (int mb = 0; mb < 4; ++mb)
            #pragma unroll
            for (int nb = 0; nb < 4; ++nb)
                acc[mb][nb] = __builtin_amdgcn_mfma_f32_16x16x32_bf16(
                    af[mb], bfr[nb], acc[mb][nb], 0, 0, 0);
        __syncthreads();
    }

    #pragma unroll
    for (int mb = 0; mb < 4; ++mb) {
        #pragma unroll
        for (int nb = 0; nb < 4; ++nb) {
            int col = n0 + wn + nb * 16 + lr;
            #pragma unroll
            for (int r = 0; r < 4; ++r) {
                int row = m0 + wm + mb * 16 + quad * 4 + r;
                float x = acc[mb][nb][r];
                if (mode == 1) {
                    x += bias[col];
                    float gl = 0.5f * x * (1.0f + erff(x * 0.70710678118654752f));
                    Cf32[(size_t)row * N + col] = gl + resid[(size_t)row * N + col];
                } else {
                    Cb16[(size_t)row * N + col] = f2bf(x);
                }
            }
        }
    }
}

// ---------------------------------------------------------------------------
// K3: ball query, wave-parallel. One wave per query; 64 lanes each test a
// contiguous 16-point chunk (lane order = index order), so prefix-sum of
// per-lane popcounts assigns the first-8-lowest-index output slots exactly
// like the sequential scan. Block = 4 waves = 4 queries sharing one
// LDS-staged ref frame.
// LDS pad: R(r)=r+(r>>4) -> read addr = lane*17+j; 17 coprime 32 => every
// bank hit by exactly 2 lanes (free). d2 math identical to ref (contract off).
// idxt layout: [(qi*2+bi)*1024+n][jf*8+s]  (32 consecutive ints per query)
// ---------------------------------------------------------------------------
#define RPAD_(r) ((r) + ((r) >> 4))

__global__ __launch_bounds__(256) void ballq_kernel(
    const float* __restrict__ xyz, int* __restrict__ idxt)
{
    #pragma clang fp contract(off)
    int blk = blockIdx.x;               // 8192 blocks: combo*256 + qgroup
    int qgroup = blk & 255;
    int combo = blk >> 8;               // qi*8 + bi*4 + jf
    int jf = combo & 3;
    int bi = (combo >> 2) & 1;
    int qi = combo >> 3;

    __shared__ float rx[N_ + (N_ >> 4)], ry[N_ + (N_ >> 4)], rz[N_ + (N_ >> 4)];
    const float* ref = xyz + (size_t)((bi * L_ + jf) * N_) * 3;
    for (int p = threadIdx.x; p < N_; p += 256) {
        rx[RPAD_(p)] = ref[p * 3 + 0];
        ry[RPAD_(p)] = ref[p * 3 + 1];
        rz[RPAD_(p)] = ref[p * 3 + 2];
    }
    __syncthreads();

    int wave = threadIdx.x >> 6;
    int lane = threadIdx.x & 63;
    int n = qgroup * 4 + wave;

    const float* qp = xyz + (size_t)((bi * L_ + qi) * N_ + n) * 3;
    float qx = qp[0], qy = qp[1], qz = qp[2];

    int base = lane * 17;               // RPAD_(lane*16)
    unsigned mask = 0;
    #pragma unroll
    for (int j = 0; j < 16; ++j) {
        float dx = qx - rx[base + j];
        float dy = qy - ry[base + j];
        float dz = qz - rz[base + j];
        float d2 = dx * dx + dy * dy;
        d2 = d2 + dz * dz;
        if (d2 < 0.04f) mask |= (1u << j);
    }

    int cnt = __popc(mask);
    int x = cnt;
    #pragma unroll
    for (int off = 1; off < 64; off <<= 1) {
        int y = __shfl_up(x, off, 64);
        if (lane >= off) x += y;
    }
    int pre = x - cnt;                       // exclusive prefix
    int total = __shfl(x, 63, 64);           // total in-radius count

    int r0 = lane * 16;
    int localFirst = mask ? (r0 + __builtin_ctz(mask)) : 0x7fffffff;
    int gfirst = localFirst;
    #pragma unroll
    for (int off = 32; off; off >>= 1) gfirst = min(gfirst, __shfl_xor(gfirst, off, 64));

    int* o = idxt + ((size_t)((qi * B_ + bi) * N_ + n)) * 32 + jf * NS_;

    unsigned m = mask;
    int pos = pre;
    while (m && pos < NS_) {
        int j = __builtin_ctz(m);
        o[pos] = r0 + j;
        m &= m - 1;
        ++pos;
    }
    if (lane == 0) {
        int padv = (total > 0) ? gfirst : 0;
        for (int s = (total < NS_ ? total : NS_); s < NS_; ++s) o[s] = padv;
    }
}

// ---------------------------------------------------------------------------
// K4: attention (round-5 structure + dot2 + XCD swizzle).
// One block (256 thr = 4 waves) per query point.  Wave w covers heads
// 2w, 2w+1.  Query mapping is XCD-aware: x=blockIdx&7 -> bi=x>>2, qi=x&3,
// n=blockIdx>>3.  Blocks go to XCDs round-robin (blockIdx%8), so each XCD
// serves exactly one (bi,qi): its K-gather set (4 MB) and V-gather set
// (4 MB) each fit the 4 MB per-XCD L2, instead of 16 MB mixed K+V.
// Phase A (lane = (hh, neighbor j)): in-lane 64-dim QK dot via v_dot2.
// Phase C (lane = (hh, dim-pair)): PV with dword V loads + spatial proj.
// ---------------------------------------------------------------------------
__global__ __launch_bounds__(256) void attn_kernel(
    const float* __restrict__ xyz, const u16* __restrict__ qkv,
    const int* __restrict__ idxt, const float* __restrict__ wsp,
    u16* __restrict__ fres)
{
    int x = blockIdx.x & 7;             // XCD id
    int bi = x >> 2;
    int qi = x & 3;
    int n = blockIdx.x >> 3;

    int wave = threadIdx.x >> 6;
    int lane = threadIdx.x & 63;
    int hh = lane >> 5;
    int j = lane & 31;
    int h = wave * 2 + hh;
    int jf = j >> 3;

    int qrow = (bi * L_ + qi) * N_ + n;                  // xyz/qkv row
    int qq = (qi * B_ + bi) * N_ + n;                    // idxt row

    __shared__ float a_s[HEADS_][32];
    __shared__ int grow_s[32];
    __shared__ float da_s[HEADS_][3];

    // --- Phase A: logits ---
    int idx = idxt[(size_t)qq * 32 + j];                 // coalesced 128B / group
    int kr = (bi * L_ + jf) * N_ + idx;

    const u16* kp = qkv + (size_t)kr * 1536 + 512 + h * 64;
    const u16* qp = qkv + (size_t)qrow * 1536 + h * 64;

    float acc = 0.f;
    #pragma unroll
    for (int c = 0; c < 8; ++c)
        acc = dot8(*(const bf16x8*)(kp + c * 8), *(const bf16x8*)(qp + c * 8), acc);

    float lg = acc * 0.125f;                             // scale = dh^-0.5

    // --- softmax over 32-lane group (xor offsets < 32 stay in group) ---
    float mx = lg;
    #pragma unroll
    for (int off = 16; off; off >>= 1) mx = fmaxf(mx, __shfl_xor(mx, off, 64));
    float e = expf(lg - mx);
    float sum = e;
    #pragma unroll
    for (int off = 16; off; off >>= 1) sum += __shfl_xor(sum, off, 64);
    float a = e / sum;
    a_s[h][j] = a;
    if (wave == 0 && hh == 0) grow_s[j] = kr;

    // --- attn * disp max (per head, over 32 neighbors) ---
    float qx = xyz[(size_t)qrow * 3 + 0];
    float qy = xyz[(size_t)qrow * 3 + 1];
    float qz = xyz[(size_t)qrow * 3 + 2];
    float tx = a * (xyz[(size_t)kr * 3 + 0] - qx);
    float ty = a * (xyz[(size_t)kr * 3 + 1] - qy);
    float tz = a * (xyz[(size_t)kr * 3 + 2] - qz);
    #pragma unroll
    for (int off = 16; off; off >>= 1) {
        tx = fmaxf(tx, __shfl_xor(tx, off, 64));
        ty = fmaxf(ty, __shfl_xor(ty, off, 64));
        tz = fmaxf(tz, __shfl_xor(tz, off, 64));
    }
    if (j == 0) { da_s[h][0] = tx; da_s[h][1] = ty; da_s[h][2] = tz; }

    __syncthreads();

    // --- Phase C: PV + spatial projection.  lane -> (hh, dim pair) ---
    int dd = (lane & 31) * 2;                            // dims dd, dd+1
    const u16* vbase = qkv + 1024 + h * 64 + dd;
    float o0 = 0.f, o1 = 0.f;
    #pragma unroll
    for (int t = 0; t < 32; ++t) {
        int krt = grow_s[t];
        float at = a_s[h][t];
        unsigned vv = *(const unsigned*)(vbase + (size_t)krt * 1536);
        o0 += at * bflo(vv);
        o1 += at * bfhi(vv);
    }
    float dax = da_s[h][0], day = da_s[h][1], daz = da_s[h][2];
    float sp0 = dax * wsp[dd]     + day * wsp[64 + dd]     + daz * wsp[128 + dd];
    float sp1 = dax * wsp[dd + 1] + day * wsp[64 + dd + 1] + daz * wsp[128 + dd + 1];

    u16* op = fres + (size_t)qrow * INNER_ + h * 64 + dd;
    unsigned outw = (unsigned)f2bf(o0 + sp0) | ((unsigned)f2bf(o1 + sp1) << 16);
    *(unsigned*)op = outw;
}

// ---------------------------------------------------------------------------
extern "C" void kernel_launch(void* const* d_in, const int* in_sizes, int n_in,
                              void* d_out, int out_size, void* d_ws, size_t ws_size,
                              hipStream_t stream) {
    const float* xyz   = (const float*)d_in[0];   // (2,4,1024,3)
    const float* feat  = (const float*)d_in[1];   // (2,4,1024,512)
    const float* gamma = (const float*)d_in[2];   // (512)
    const float* beta  = (const float*)d_in[3];   // (512)
    const float* wqkv  = (const float*)d_in[4];   // (512,1536)
    const float* wsp   = (const float*)d_in[5];   // (3,64)
    const float* wout  = (const float*)d_in[6];   // (512,512)
    const float* bout  = (const float*)d_in[7];   // (512)
    float* out = (float*)d_out;

    char* ws = (char*)d_ws;
    u16* normf = (u16*)ws;                 ws += (size_t)ROWS_ * DIM_ * 2;        // 8 MB
    u16* wqkvT = (u16*)ws;                 ws += (size_t)3 * INNER_ * DIM_ * 2;   // 1.5 MB
    u16* woutT = (u16*)ws;                 ws += (size_t)DIM_ * INNER_ * 2;       // 0.5 MB
    u16* qkv   = (u16*)ws;                 ws += (size_t)ROWS_ * 3 * INNER_ * 2;  // 24 MB
    int* idxt  = (int*)ws;                 ws += (size_t)L_ * NFR_ * N_ * NS_ * 4;// 1 MB
    u16* fres  = normf;   // alias: normf is dead after GEMM1 completes

    transpose_w<<<4096, 256, 0, stream>>>(wqkv, wout, wqkvT, woutT);
    ln_kernel<<<ROWS_, 256, 0, stream>>>(feat, gamma, beta, normf);
    // qkv = normf @ w_qkv : M=8192, N=1536, K=512
    gemm_bt<<<64 * 12, 256, 0, stream>>>(normf, wqkvT, qkv, nullptr,
                                         ROWS_, 3 * INNER_, DIM_, 12, 0, nullptr, nullptr);
    ballq_kernel<<<32 * 256, 256, 0, stream>>>(xyz, idxt);
    attn_kernel<<<ROWS_, 256, 0, stream>>>(xyz, qkv, idxt, wsp, fres);
    // out = gelu(fres @ w_out + b_out) + feature : M=8192, N=512, K=512
    gemm_bt<<<64 * 4, 256, 0, stream>>>(fres, woutT, nullptr, out,
                                        ROWS_, DIM_, INNER_, 4, 1, bout, feat);
}

// Round 8
// 233.509 us; speedup vs baseline: 1.0879x; 1.0154x over previous
//
#include <hip/hip_runtime.h>
#include <hip/hip_bf16.h>

// Problem constants (b=2, l=4, n=1024, dim=512, heads=8, dh=64, nsample=8)
// All d_in / d_out buffers are FLOAT32 (reference dtypes). Internal compute
// uses bf16 MFMA (allowed by the bf16-mode absmax threshold 0.105).
#define B_ 2
#define L_ 4
#define N_ 1024
#define DIM_ 512
#define INNER_ 512
#define HEADS_ 8
#define DH_ 64
#define NS_ 8
#define NFR_ (B_ * L_)            // 8 flat frames
#define ROWS_ (B_ * L_ * N_)      // 8192 point rows

typedef unsigned short u16;
typedef __attribute__((ext_vector_type(8))) short bf16x8;
typedef __attribute__((ext_vector_type(4))) float f32x4;

__device__ inline float bf2f(u16 u) {
    union { unsigned i; float f; } c; c.i = ((unsigned)u) << 16; return c.f;
}
__device__ inline float bflo(unsigned v) {   // low bf16 of dword -> f32
    union { unsigned i; float f; } c; c.i = v << 16; return c.f;
}
__device__ inline float bfhi(unsigned v) {   // high bf16 of dword -> f32
    union { unsigned i; float f; } c; c.i = v & 0xffff0000u; return c.f;
}
__device__ inline u16 f2bf(float x) {
    __hip_bfloat16 h = __float2bfloat16(x);  // round-to-nearest-even
    return *reinterpret_cast<u16*>(&h);
}

// 8-element bf16 dot with f32 accumulate; v_dot2_f32_bf16 when available.
#if __has_builtin(__builtin_amdgcn_fdot2_f32_bf16)
typedef __bf16 bf2v __attribute__((ext_vector_type(2)));
__device__ inline float dot8(bf16x8 a, bf16x8 b, float acc) {
    union U { bf16x8 v; bf2v p[4]; };
    U ua, ub; ua.v = a; ub.v = b;
    #pragma unroll
    for (int i = 0; i < 4; ++i)
        acc = __builtin_amdgcn_fdot2_f32_bf16(ua.p[i], ub.p[i], acc, false);
    return acc;
}
#else
__device__ inline float dot8(bf16x8 a, bf16x8 b, float acc) {
    #pragma unroll
    for (int e = 0; e < 8; ++e) acc += bf2f((u16)a[e]) * bf2f((u16)b[e]);
    return acc;
}
#endif

// ---------------------------------------------------------------------------
// K0: tiled transpose + bf16 cast.  64x64 LDS tile (pad 65 -> conflict-free),
// coalesced f32 reads AND coalesced 16B bf16 writes (the old version wrote
// 2B at stride 1KB: 64 partial-line writes per wave-instr).
// blocks 0..191: wqkv (512x1536 -> 1536x512); 192..255: wout (512x512).
// ---------------------------------------------------------------------------
__global__ __launch_bounds__(256) void transpose_cvt(
    const float* __restrict__ wqkv, const float* __restrict__ wout,
    u16* __restrict__ wqkvT, u16* __restrict__ woutT)
{
    const float* src; u16* dst; int R, C, tr, tc;
    int b = blockIdx.x;
    if (b < 192) { src = wqkv; dst = wqkvT; R = 512; C = 1536; tr = b / 24; tc = b % 24; }
    else { b -= 192; src = wout; dst = woutT; R = 512; C = 512; tr = b / 8; tc = b % 8; }
    int r0 = tr * 64, c0 = tc * 64;
    int t = threadIdx.x;

    __shared__ float tile[64][65];

    int rr = t >> 2, cs = (t & 3) * 16;
    const float* sp = src + (size_t)(r0 + rr) * C + c0 + cs;
    #pragma unroll
    for (int e = 0; e < 16; e += 4) {
        f32x4 v = *(const f32x4*)(sp + e);
        tile[rr][cs + e + 0] = v[0];
        tile[rr][cs + e + 1] = v[1];
        tile[rr][cs + e + 2] = v[2];
        tile[rr][cs + e + 3] = v[3];
    }
    __syncthreads();

    int c = t >> 2, ks = (t & 3) * 16;
    u16 outv[16];
    #pragma unroll
    for (int e = 0; e < 16; ++e) outv[e] = f2bf(tile[ks + e][c]);
    u16* dp = dst + (size_t)(c0 + c) * R + r0 + ks;
    *(bf16x8*)(dp)     = *(bf16x8*)&outv[0];
    *(bf16x8*)(dp + 8) = *(bf16x8*)&outv[8];
}

// ---------------------------------------------------------------------------
// K1: LayerNorm over channel dim (512) -> bf16 normf.  One block per row.
// ---------------------------------------------------------------------------
__global__ __launch_bounds__(256) void ln_kernel(
    const float* __restrict__ f, const float* __restrict__ g,
    const float* __restrict__ b, u16* __restrict__ o)
{
    int row = blockIdx.x;
    int t = threadIdx.x;
    const float* fr = f + (size_t)row * DIM_;
    float x0 = fr[t], x1 = fr[t + 256];

    __shared__ float red[4];
    float s = x0 + x1;
    #pragma unroll
    for (int off = 32; off; off >>= 1) s += __shfl_xor(s, off, 64);
    if ((t & 63) == 0) red[t >> 6] = s;
    __syncthreads();
    float mu = (red[0] + red[1] + red[2] + red[3]) * (1.0f / 512.0f);
    __syncthreads();

    float d0 = x0 - mu, d1 = x1 - mu;
    float q = d0 * d0 + d1 * d1;
    #pragma unroll
    for (int off = 32; off; off >>= 1) q += __shfl_xor(q, off, 64);
    if ((t & 63) == 0) red[t >> 6] = q;
    __syncthreads();
    float var = (red[0] + red[1] + red[2] + red[3]) * (1.0f / 512.0f);
    float inv = rsqrtf(var + 1e-5f);

    o[(size_t)row * DIM_ + t]       = f2bf(d0 * inv * g[t]       + b[t]);
    o[(size_t)row * DIM_ + t + 256] = f2bf(d1 * inv * g[t + 256] + b[t + 256]);
}

// ---------------------------------------------------------------------------
// K2/K5: MFMA bf16 GEMM, C[M,N] = A[M,K] @ Bt[N,K]^T.
// 128x128 block tile, BK=32, 256 threads (4 waves, each 64x64).
// mode 0: Cb16 = bf16(acc)                          (qkv, bf16 ws)
// mode 1: Cf32 = gelu(acc + bias) + resid           (final output, f32)
// ---------------------------------------------------------------------------
__global__ __launch_bounds__(256) void gemm_bt(
    const u16* __restrict__ A, const u16* __restrict__ Bt,
    u16* __restrict__ Cb16, float* __restrict__ Cf32,
    int M, int N, int K, int nb128, int mode,
    const float* __restrict__ bias, const float* __restrict__ resid)
{
    __shared__ u16 As[128 * 40];   // stride 40 bf16 = 80B (16B aligned)
    __shared__ u16 Bs[128 * 40];

    int bx = blockIdx.x % nb128;
    int by = blockIdx.x / nb128;
    int m0 = by * 128, n0 = bx * 128;
    int t = threadIdx.x;
    int wave = t >> 6, lane = t & 63;
    int lr = lane & 15, quad = lane >> 4;
    int wm = (wave >> 1) * 64, wn = (wave & 1) * 64;

    f32x4 acc[4][4];
    #pragma unroll
    for (int i = 0; i < 4; ++i)
        #pragma unroll
        for (int j = 0; j < 4; ++j)
            acc[i][j] = {0.f, 0.f, 0.f, 0.f};

    for (int k0 = 0; k0 < K; k0 += 32) {
        #pragma unroll
        for (int p = 0; p < 2; ++p) {
            int c = t + p * 256;           // 0..511
            int r = c >> 2;                // 0..127
            int kc = (c & 3) * 8;          // 0,8,16,24
            *(bf16x8*)&As[r * 40 + kc] = *(const bf16x8*)(A + (size_t)(m0 + r) * K + k0 + kc);
            *(bf16x8*)&Bs[r * 40 + kc] = *(const bf16x8*)(Bt + (size_t)(n0 + r) * K + k0 + kc);
        }
        __syncthreads();

        bf16x8 af[4], bfr[4];
        #pragma unroll
        for (int mb = 0; mb < 4; ++mb)
            af[mb] = *(const bf16x8*)&As[(wm + mb * 16 + lr) * 40 + quad * 8];
        #pragma unroll
        for (int nb = 0; nb < 4; ++nb)
            bfr[nb] = *(const bf16x8*)&Bs[(wn + nb * 16 + lr) * 40 + quad * 8];
        #pragma unroll
        for (int mb = 0; mb < 4; ++mb)
            #pragma unroll
            for (int nb = 0; nb < 4; ++nb)
                acc[mb][nb] = __builtin_amdgcn_mfma_f32_16x16x32_bf16(
                    af[mb], bfr[nb], acc[mb][nb], 0, 0, 0);
        __syncthreads();
    }

    #pragma unroll
    for (int mb = 0; mb < 4; ++mb) {
        #pragma unroll
        for (int nb = 0; nb < 4; ++nb) {
            int col = n0 + wn + nb * 16 + lr;
            #pragma unroll
            for (int r = 0; r < 4; ++r) {
                int row = m0 + wm + mb * 16 + quad * 4 + r;
                float x = acc[mb][nb][r];
                if (mode == 1) {
                    x += bias[col];
                    float gl = 0.5f * x * (1.0f + erff(x * 0.70710678118654752f));
                    Cf32[(size_t)row * N + col] = gl + resid[(size_t)row * N + col];
                } else {
                    Cb16[(size_t)row * N + col] = f2bf(x);
                }
            }
        }
    }
}

// ---------------------------------------------------------------------------
// K3: ball query, wave-parallel. One wave per query; 64 lanes each test a
// contiguous 16-point chunk (lane order = index order), so prefix-sum of
// per-lane popcounts assigns the first-8-lowest-index output slots exactly
// like the sequential scan. Block = 4 waves = 4 queries sharing one
// LDS-staged ref frame.
// LDS pad: R(r)=r+(r>>4) -> read addr = lane*17+j; 17 coprime 32 => every
// bank hit by exactly 2 lanes (free). d2 math identical to ref (contract off).
// idxt layout: [(qi*2+bi)*1024+n][jf*8+s]  (32 consecutive ints per query)
// ---------------------------------------------------------------------------
#define RPAD_(r) ((r) + ((r) >> 4))

__global__ __launch_bounds__(256) void ballq_kernel(
    const float* __restrict__ xyz, int* __restrict__ idxt)
{
    #pragma clang fp contract(off)
    int blk = blockIdx.x;               // 8192 blocks: combo*256 + qgroup
    int qgroup = blk & 255;
    int combo = blk >> 8;               // qi*8 + bi*4 + jf
    int jf = combo & 3;
    int bi = (combo >> 2) & 1;
    int qi = combo >> 3;

    __shared__ float rx[N_ + (N_ >> 4)], ry[N_ + (N_ >> 4)], rz[N_ + (N_ >> 4)];
    const float* ref = xyz + (size_t)((bi * L_ + jf) * N_) * 3;
    for (int p = threadIdx.x; p < N_; p += 256) {
        rx[RPAD_(p)] = ref[p * 3 + 0];
        ry[RPAD_(p)] = ref[p * 3 + 1];
        rz[RPAD_(p)] = ref[p * 3 + 2];
    }
    __syncthreads();

    int wave = threadIdx.x >> 6;
    int lane = threadIdx.x & 63;
    int n = qgroup * 4 + wave;

    const float* qp = xyz + (size_t)((bi * L_ + qi) * N_ + n) * 3;
    float qx = qp[0], qy = qp[1], qz = qp[2];

    int base = lane * 17;               // RPAD_(lane*16)
    unsigned mask = 0;
    #pragma unroll
    for (int j = 0; j < 16; ++j) {
        float dx = qx - rx[base + j];
        float dy = qy - ry[base + j];
        float dz = qz - rz[base + j];
        float d2 = dx * dx + dy * dy;
        d2 = d2 + dz * dz;
        if (d2 < 0.04f) mask |= (1u << j);
    }

    int cnt = __popc(mask);
    int x = cnt;
    #pragma unroll
    for (int off = 1; off < 64; off <<= 1) {
        int y = __shfl_up(x, off, 64);
        if (lane >= off) x += y;
    }
    int pre = x - cnt;                       // exclusive prefix
    int total = __shfl(x, 63, 64);           // total in-radius count

    int r0 = lane * 16;
    int localFirst = mask ? (r0 + __builtin_ctz(mask)) : 0x7fffffff;
    int gfirst = localFirst;
    #pragma unroll
    for (int off = 32; off; off >>= 1) gfirst = min(gfirst, __shfl_xor(gfirst, off, 64));

    int* o = idxt + ((size_t)((qi * B_ + bi) * N_ + n)) * 32 + jf * NS_;

    unsigned m = mask;
    int pos = pre;
    while (m && pos < NS_) {
        int j = __builtin_ctz(m);
        o[pos] = r0 + j;
        m &= m - 1;
        ++pos;
    }
    if (lane == 0) {
        int padv = (total > 0) ? gfirst : 0;
        for (int s = (total < NS_ ? total : NS_); s < NS_; ++s) o[s] = padv;
    }
}

// ---------------------------------------------------------------------------
// K4: attention (round-7 structure + forced ILP).
// __launch_bounds__(256,4): cap 128 VGPR / 16 waves-CU — round-7's VGPR=32
// build serialized the gathers (only ~4-8 loads in flight -> latency-bound
// at 26% VALU, 8% HBM).  K/Q fragments are loaded into register arrays
// before the dot; phase C runs two half-batches of 16 outstanding V loads.
// XCD swizzle retained (FETCH 100->35 MB, measured r7).
// ---------------------------------------------------------------------------
__global__ __launch_bounds__(256, 4) void attn_kernel(
    const float* __restrict__ xyz, const u16* __restrict__ qkv,
    const int* __restrict__ idxt, const float* __restrict__ wsp,
    u16* __restrict__ fres)
{
    int x = blockIdx.x & 7;             // XCD id
    int bi = x >> 2;
    int qi = x & 3;
    int n = blockIdx.x >> 3;

    int wave = threadIdx.x >> 6;
    int lane = threadIdx.x & 63;
    int hh = lane >> 5;
    int j = lane & 31;
    int h = wave * 2 + hh;
    int jf = j >> 3;

    int qrow = (bi * L_ + qi) * N_ + n;                  // xyz/qkv row
    int qq = (qi * B_ + bi) * N_ + n;                    // idxt row

    __shared__ float a_s[HEADS_][32];
    __shared__ int grow_s[32];
    __shared__ float da_s[HEADS_][3];

    // --- Phase A: logits.  Q and K fragments pre-loaded into registers so
    // all 16 16B loads are in flight before the first dot consumes them. ---
    const u16* qp = qkv + (size_t)qrow * 1536 + h * 64;
    bf16x8 qv[8];
    #pragma unroll
    for (int c = 0; c < 8; ++c) qv[c] = *(const bf16x8*)(qp + c * 8);

    int idx = idxt[(size_t)qq * 32 + j];                 // coalesced 128B / group
    int kr = (bi * L_ + jf) * N_ + idx;

    const u16* kp = qkv + (size_t)kr * 1536 + 512 + h * 64;
    bf16x8 kv[8];
    #pragma unroll
    for (int c = 0; c < 8; ++c) kv[c] = *(const bf16x8*)(kp + c * 8);

    float acc = 0.f;
    #pragma unroll
    for (int c = 0; c < 8; ++c) acc = dot8(kv[c], qv[c], acc);
    float lg = acc * 0.125f;                             // scale = dh^-0.5

    // --- softmax over 32-lane group (xor offsets < 32 stay in group) ---
    float mx = lg;
    #pragma unroll
    for (int off = 16; off; off >>= 1) mx = fmaxf(mx, __shfl_xor(mx, off, 64));
    float e = expf(lg - mx);
    float sum = e;
    #pragma unroll
    for (int off = 16; off; off >>= 1) sum += __shfl_xor(sum, off, 64);
    float a = e / sum;
    a_s[h][j] = a;
    if (wave == 0 && hh == 0) grow_s[j] = kr;

    // --- attn * disp max (per head, over 32 neighbors) ---
    float qx = xyz[(size_t)qrow * 3 + 0];
    float qy = xyz[(size_t)qrow * 3 + 1];
    float qz = xyz[(size_t)qrow * 3 + 2];
    float tx = a * (xyz[(size_t)kr * 3 + 0] - qx);
    float ty = a * (xyz[(size_t)kr * 3 + 1] - qy);
    float tz = a * (xyz[(size_t)kr * 3 + 2] - qz);
    #pragma unroll
    for (int off = 16; off; off >>= 1) {
        tx = fmaxf(tx, __shfl_xor(tx, off, 64));
        ty = fmaxf(ty, __shfl_xor(ty, off, 64));
        tz = fmaxf(tz, __shfl_xor(tz, off, 64));
    }
    if (j == 0) { da_s[h][0] = tx; da_s[h][1] = ty; da_s[h][2] = tz; }

    __syncthreads();

    // --- Phase C: PV + spatial projection, two half-batches of 16
    // outstanding V loads each (forced ILP). lane -> (hh, dim pair) ---
    int dd = (lane & 31) * 2;                            // dims dd, dd+1
    const u16* vbase = qkv + 1024 + h * 64 + dd;
    float o0 = 0.f, o1 = 0.f;
    #pragma unroll
    for (int half = 0; half < 2; ++half) {
        unsigned vv[16];
        float at[16];
        #pragma unroll
        for (int t = 0; t < 16; ++t) {
            int tt = half * 16 + t;
            at[t] = a_s[h][tt];
            vv[t] = *(const unsigned*)(vbase + (size_t)grow_s[tt] * 1536);
        }
        #pragma unroll
        for (int t = 0; t < 16; ++t) {
            o0 += at[t] * bflo(vv[t]);
            o1 += at[t] * bfhi(vv[t]);
        }
    }
    float dax = da_s[h][0], day = da_s[h][1], daz = da_s[h][2];
    float sp0 = dax * wsp[dd]     + day * wsp[64 + dd]     + daz * wsp[128 + dd];
    float sp1 = dax * wsp[dd + 1] + day * wsp[64 + dd + 1] + daz * wsp[128 + dd + 1];

    u16* op = fres + (size_t)qrow * INNER_ + h * 64 + dd;
    unsigned outw = (unsigned)f2bf(o0 + sp0) | ((unsigned)f2bf(o1 + sp1) << 16);
    *(unsigned*)op = outw;
}

// ---------------------------------------------------------------------------
extern "C" void kernel_launch(void* const* d_in, const int* in_sizes, int n_in,
                              void* d_out, int out_size, void* d_ws, size_t ws_size,
                              hipStream_t stream) {
    const float* xyz   = (const float*)d_in[0];   // (2,4,1024,3)
    const float* feat  = (const float*)d_in[1];   // (2,4,1024,512)
    const float* gamma = (const float*)d_in[2];   // (512)
    const float* beta  = (const float*)d_in[3];   // (512)
    const float* wqkv  = (const float*)d_in[4];   // (512,1536)
    const float* wsp   = (const float*)d_in[5];   // (3,64)
    const float* wout  = (const float*)d_in[6];   // (512,512)
    const float* bout  = (const float*)d_in[7];   // (512)
    float* out = (float*)d_out;

    char* ws = (char*)d_ws;
    u16* normf = (u16*)ws;                 ws += (size_t)ROWS_ * DIM_ * 2;        // 8 MB
    u16* wqkvT = (u16*)ws;                 ws += (size_t)3 * INNER_ * DIM_ * 2;   // 1.5 MB
    u16* woutT = (u16*)ws;                 ws += (size_t)DIM_ * INNER_ * 2;       // 0.5 MB
    u16* qkv   = (u16*)ws;                 ws += (size_t)ROWS_ * 3 * INNER_ * 2;  // 24 MB
    int* idxt  = (int*)ws;                 ws += (size_t)L_ * NFR_ * N_ * NS_ * 4;// 1 MB
    u16* fres  = normf;   // alias: normf is dead after GEMM1 completes

    transpose_cvt<<<256, 256, 0, stream>>>(wqkv, wout, wqkvT, woutT);
    ln_kernel<<<ROWS_, 256, 0, stream>>>(feat, gamma, beta, normf);
    // qkv = normf @ w_qkv : M=8192, N=1536, K=512
    gemm_bt<<<64 * 12, 256, 0, stream>>>(normf, wqkvT, qkv, nullptr,
                                         ROWS_, 3 * INNER_, DIM_, 12, 0, nullptr, nullptr);
    ballq_kernel<<<32 * 256, 256, 0, stream>>>(xyz, idxt);
    attn_kernel<<<ROWS_, 256, 0, stream>>>(xyz, qkv, idxt, wsp, fres);
    // out = gelu(fres @ w_out + b_out) + feature : M=8192, N=512, K=512
    gemm_bt<<<64 * 4, 256, 0, stream>>>(fres, woutT, nullptr, out,
                                        ROWS_, DIM_, INNER_, 4, 1, bout, feat);
}

// Round 10
// 220.924 us; speedup vs baseline: 1.1499x; 1.0570x over previous
//
#include <hip/hip_runtime.h>
#include <hip/hip_bf16.h>

// Problem constants (b=2, l=4, n=1024, dim=512, heads=8, dh=64, nsample=8)
// All d_in / d_out buffers are FLOAT32 (reference dtypes). Internal compute
// uses bf16 MFMA (allowed by the bf16-mode absmax threshold 0.105).
#define B_ 2
#define L_ 4
#define N_ 1024
#define DIM_ 512
#define INNER_ 512
#define HEADS_ 8
#define DH_ 64
#define NS_ 8
#define NFR_ (B_ * L_)            // 8 flat frames
#define ROWS_ (B_ * L_ * N_)      // 8192 point rows

typedef unsigned short u16;
typedef __attribute__((ext_vector_type(8))) short bf16x8;
typedef __attribute__((ext_vector_type(4))) float f32x4;

__device__ inline float bf2f(u16 u) {
    union { unsigned i; float f; } c; c.i = ((unsigned)u) << 16; return c.f;
}
__device__ inline float bflo(unsigned v) {   // low bf16 of dword -> f32
    union { unsigned i; float f; } c; c.i = v << 16; return c.f;
}
__device__ inline float bfhi(unsigned v) {   // high bf16 of dword -> f32
    union { unsigned i; float f; } c; c.i = v & 0xffff0000u; return c.f;
}
__device__ inline u16 f2bf(float x) {
    __hip_bfloat16 h = __float2bfloat16(x);  // round-to-nearest-even
    return *reinterpret_cast<u16*>(&h);
}

// 8-element bf16 dot with f32 accumulate; v_dot2_f32_bf16 when available.
#if __has_builtin(__builtin_amdgcn_fdot2_f32_bf16)
typedef __bf16 bf2v __attribute__((ext_vector_type(2)));
__device__ inline float dot8(bf16x8 a, bf16x8 b, float acc) {
    union U { bf16x8 v; bf2v p[4]; };
    U ua, ub; ua.v = a; ub.v = b;
    #pragma unroll
    for (int i = 0; i < 4; ++i)
        acc = __builtin_amdgcn_fdot2_f32_bf16(ua.p[i], ub.p[i], acc, false);
    return acc;
}
#else
__device__ inline float dot8(bf16x8 a, bf16x8 b, float acc) {
    #pragma unroll
    for (int e = 0; e < 8; ++e) acc += bf2f((u16)a[e]) * bf2f((u16)b[e]);
    return acc;
}
#endif

// ---------------------------------------------------------------------------
// K0: tiled transpose + bf16 cast.  64x64 LDS tile (pad 65 -> conflict-free),
// coalesced f32 reads AND coalesced 16B bf16 writes.
// blocks 0..191: wqkv (512x1536 -> 1536x512); 192..255: wout (512x512).
// ---------------------------------------------------------------------------
__global__ __launch_bounds__(256) void transpose_cvt(
    const float* __restrict__ wqkv, const float* __restrict__ wout,
    u16* __restrict__ wqkvT, u16* __restrict__ woutT)
{
    const float* src; u16* dst; int R, C, tr, tc;
    int b = blockIdx.x;
    if (b < 192) { src = wqkv; dst = wqkvT; R = 512; C = 1536; tr = b / 24; tc = b % 24; }
    else { b -= 192; src = wout; dst = woutT; R = 512; C = 512; tr = b / 8; tc = b % 8; }
    int r0 = tr * 64, c0 = tc * 64;
    int t = threadIdx.x;

    __shared__ float tile[64][65];

    int rr = t >> 2, cs = (t & 3) * 16;
    const float* sp = src + (size_t)(r0 + rr) * C + c0 + cs;
    #pragma unroll
    for (int e = 0; e < 16; e += 4) {
        f32x4 v = *(const f32x4*)(sp + e);
        tile[rr][cs + e + 0] = v[0];
        tile[rr][cs + e + 1] = v[1];
        tile[rr][cs + e + 2] = v[2];
        tile[rr][cs + e + 3] = v[3];
    }
    __syncthreads();

    int c = t >> 2, ks = (t & 3) * 16;
    u16 outv[16];
    #pragma unroll
    for (int e = 0; e < 16; ++e) outv[e] = f2bf(tile[ks + e][c]);
    u16* dp = dst + (size_t)(c0 + c) * R + r0 + ks;
    *(bf16x8*)(dp)     = *(bf16x8*)&outv[0];
    *(bf16x8*)(dp + 8) = *(bf16x8*)&outv[8];
}

// ---------------------------------------------------------------------------
// K1: LayerNorm over channel dim (512) -> bf16 normf.  One block per row.
// ---------------------------------------------------------------------------
__global__ __launch_bounds__(256) void ln_kernel(
    const float* __restrict__ f, const float* __restrict__ g,
    const float* __restrict__ b, u16* __restrict__ o)
{
    int row = blockIdx.x;
    int t = threadIdx.x;
    const float* fr = f + (size_t)row * DIM_;
    float x0 = fr[t], x1 = fr[t + 256];

    __shared__ float red[4];
    float s = x0 + x1;
    #pragma unroll
    for (int off = 32; off; off >>= 1) s += __shfl_xor(s, off, 64);
    if ((t & 63) == 0) red[t >> 6] = s;
    __syncthreads();
    float mu = (red[0] + red[1] + red[2] + red[3]) * (1.0f / 512.0f);
    __syncthreads();

    float d0 = x0 - mu, d1 = x1 - mu;
    float q = d0 * d0 + d1 * d1;
    #pragma unroll
    for (int off = 32; off; off >>= 1) q += __shfl_xor(q, off, 64);
    if ((t & 63) == 0) red[t >> 6] = q;
    __syncthreads();
    float var = (red[0] + red[1] + red[2] + red[3]) * (1.0f / 512.0f);
    float inv = rsqrtf(var + 1e-5f);

    o[(size_t)row * DIM_ + t]       = f2bf(d0 * inv * g[t]       + b[t]);
    o[(size_t)row * DIM_ + t + 256] = f2bf(d1 * inv * g[t + 256] + b[t + 256]);
}

// ---------------------------------------------------------------------------
// K2/K5: MFMA bf16 GEMM, C[M,N] = A[M,K] @ Bt[N,K]^T.
// 128x128 block tile, BK=32, 256 threads (4 waves, each 64x64).
// mode 0: Cb16 = bf16(acc)                          (qkv, bf16 ws)
// mode 1: Cf32 = gelu(acc + bias) + resid           (final output, f32)
// ---------------------------------------------------------------------------
__global__ __launch_bounds__(256) void gemm_bt(
    const u16* __restrict__ A, const u16* __restrict__ Bt,
    u16* __restrict__ Cb16, float* __restrict__ Cf32,
    int M, int N, int K, int nb128, int mode,
    const float* __restrict__ bias, const float* __restrict__ resid)
{
    __shared__ u16 As[128 * 40];   // stride 40 bf16 = 80B (16B aligned)
    __shared__ u16 Bs[128 * 40];

    int bx = blockIdx.x % nb128;
    int by = blockIdx.x / nb128;
    int m0 = by * 128, n0 = bx * 128;
    int t = threadIdx.x;
    int wave = t >> 6, lane = t & 63;
    int lr = lane & 15, quad = lane >> 4;
    int wm = (wave >> 1) * 64, wn = (wave & 1) * 64;

    f32x4 acc[4][4];
    #pragma unroll
    for (int i = 0; i < 4; ++i)
        #pragma unroll
        for (int j = 0; j < 4; ++j)
            acc[i][j] = {0.f, 0.f, 0.f, 0.f};

    for (int k0 = 0; k0 < K; k0 += 32) {
        #pragma unroll
        for (int p = 0; p < 2; ++p) {
            int c = t + p * 256;           // 0..511
            int r = c >> 2;                // 0..127
            int kc = (c & 3) * 8;          // 0,8,16,24
            *(bf16x8*)&As[r * 40 + kc] = *(const bf16x8*)(A + (size_t)(m0 + r) * K + k0 + kc);
            *(bf16x8*)&Bs[r * 40 + kc] = *(const bf16x8*)(Bt + (size_t)(n0 + r) * K + k0 + kc);
        }
        __syncthreads();

        bf16x8 af[4], bfr[4];
        #pragma unroll
        for (int mb = 0; mb < 4; ++mb)
            af[mb] = *(const bf16x8*)&As[(wm + mb * 16 + lr) * 40 + quad * 8];
        #pragma unroll
        for (int nb = 0; nb < 4; ++nb)
            bfr[nb] = *(const bf16x8*)&Bs[(wn + nb * 16 + lr) * 40 + quad * 8];
        #pragma unroll
        for (int mb = 0; mb < 4; ++mb)
            #pragma unroll
            for (int nb = 0; nb < 4; ++nb)
                acc[mb][nb] = __builtin_amdgcn_mfma_f32_16x16x32_bf16(
                    af[mb], bfr[nb], acc[mb][nb], 0, 0, 0);
        __syncthreads();
    }

    #pragma unroll
    for (int mb = 0; mb < 4; ++mb) {
        #pragma unroll
        for (int nb = 0; nb < 4; ++nb) {
            int col = n0 + wn + nb * 16 + lr;
            #pragma unroll
            for (int r = 0; r < 4; ++r) {
                int row = m0 + wm + mb * 16 + quad * 4 + r;
                float x = acc[mb][nb][r];
                if (mode == 1) {
                    x += bias[col];
                    float gl = 0.5f * x * (1.0f + erff(x * 0.70710678118654752f));
                    Cf32[(size_t)row * N + col] = gl + resid[(size_t)row * N + col];
                } else {
                    Cb16[(size_t)row * N + col] = f2bf(x);
                }
            }
        }
    }
}

// ---------------------------------------------------------------------------
// K3: ball query, wave-parallel, staging-amortized.  One block per
// (bi, jf, query-chunk): stage the (bi,jf) ref frame into padded LDS ONCE,
// then loop over all 4 query frames qi (4x fewer blocks / stagings than the
// per-(qi,bi,jf) version).  One wave per query per qi iteration; 64 lanes
// each test a contiguous 16-point chunk; prefix-sum of per-lane popcounts
// assigns the first-8-lowest-index slots exactly like the sequential scan.
// LDS pad: R(r)=r+(r>>4) -> read addr = lane*17+j; 17 coprime 32 => 2-way
// aliasing only (free).  d2 math identical to ref (contract off).
// idxt layout: [(qi*2+bi)*1024+n][jf*8+s]  (32 consecutive ints per query)
// ---------------------------------------------------------------------------
#define RPAD_(r) ((r) + ((r) >> 4))

__global__ __launch_bounds__(256) void ballq_kernel(
    const float* __restrict__ xyz, int* __restrict__ idxt)
{
    #pragma clang fp contract(off)
    int chunk = blockIdx.x & 255;       // 2048 blocks: (bi*4+jf)*256 + chunk
    int combo = blockIdx.x >> 8;
    int jf = combo & 3;
    int bi = combo >> 2;

    __shared__ float rx[N_ + (N_ >> 4)], ry[N_ + (N_ >> 4)], rz[N_ + (N_ >> 4)];
    const float* ref = xyz + (size_t)((bi * L_ + jf) * N_) * 3;
    for (int p = threadIdx.x; p < N_; p += 256) {
        rx[RPAD_(p)] = ref[p * 3 + 0];
        ry[RPAD_(p)] = ref[p * 3 + 1];
        rz[RPAD_(p)] = ref[p * 3 + 2];
    }
    __syncthreads();

    int wave = threadIdx.x >> 6;
    int lane = threadIdx.x & 63;
    int n = chunk * 4 + wave;
    int base = lane * 17;               // RPAD_(lane*16)
    int r0 = lane * 16;

    for (int qi = 0; qi < L_; ++qi) {
        const float* qp = xyz + (size_t)((bi * L_ + qi) * N_ + n) * 3;
        float qx = qp[0], qy = qp[1], qz = qp[2];

        unsigned mask = 0;
        #pragma unroll
        for (int j = 0; j < 16; ++j) {
            float dx = qx - rx[base + j];
            float dy = qy - ry[base + j];
            float dz = qz - rz[base + j];
            float d2 = dx * dx + dy * dy;
            d2 = d2 + dz * dz;
            if (d2 < 0.04f) mask |= (1u << j);
        }

        int cnt = __popc(mask);
        int x = cnt;
        #pragma unroll
        for (int off = 1; off < 64; off <<= 1) {
            int y = __shfl_up(x, off, 64);
            if (lane >= off) x += y;
        }
        int pre = x - cnt;                       // exclusive prefix
        int total = __shfl(x, 63, 64);           // total in-radius count

        int localFirst = mask ? (r0 + __builtin_ctz(mask)) : 0x7fffffff;
        int gfirst = localFirst;
        #pragma unroll
        for (int off = 32; off; off >>= 1) gfirst = min(gfirst, __shfl_xor(gfirst, off, 64));

        int* o = idxt + ((size_t)((qi * B_ + bi) * N_ + n)) * 32 + jf * NS_;

        unsigned m = mask;
        int pos = pre;
        while (m && pos < NS_) {
            int j = __builtin_ctz(m);
            o[pos] = r0 + j;
            m &= m - 1;
            ++pos;
        }
        if (lane == 0) {
            int padv = (total > 0) ? gfirst : 0;
            for (int s = (total < NS_ ? total : NS_); s < NS_; ++s) o[s] = padv;
        }
    }
}

// ---------------------------------------------------------------------------
// K4: attention with scheduler-fenced gather batching.
// Round-8's batching failed: VGPR_Count stayed 32 — the allocator sank each
// load to its use.  sched_barrier(0) after the load loops makes sinking
// illegal, forcing 16 (phase A) / 32 (phase C) results live => one latency
// exposure per phase.  __launch_bounds__(256,4) caps at 128 VGPR.
// XCD swizzle retained (FETCH 100->35 MB, measured r7).
// ---------------------------------------------------------------------------
__global__ __launch_bounds__(256, 4) void attn_kernel(
    const float* __restrict__ xyz, const u16* __restrict__ qkv,
    const int* __restrict__ idxt, const float* __restrict__ wsp,
    u16* __restrict__ fres)
{
    int x = blockIdx.x & 7;             // XCD id
    int bi = x >> 2;
    int qi = x & 3;
    int n = blockIdx.x >> 3;

    int wave = threadIdx.x >> 6;
    int lane = threadIdx.x & 63;
    int hh = lane >> 5;
    int j = lane & 31;
    int h = wave * 2 + hh;
    int jf = j >> 3;

    int qrow = (bi * L_ + qi) * N_ + n;                  // xyz/qkv row
    int qq = (qi * B_ + bi) * N_ + n;                    // idxt row

    __shared__ float a_s[HEADS_][32];
    __shared__ int grow_s[32];
    __shared__ float da_s[HEADS_][3];

    // --- Phase A: batch-issue idx, then all 16 K/Q fragment loads + the 3
    // neighbor-xyz loads; fence; then consume. ---
    int idx = idxt[(size_t)qq * 32 + j];                 // coalesced 128B / group
    int kr = (bi * L_ + jf) * N_ + idx;

    const u16* qp = qkv + (size_t)qrow * 1536 + h * 64;
    const u16* kp = qkv + (size_t)kr * 1536 + 512 + h * 64;
    bf16x8 qv[8], kv[8];
    #pragma unroll
    for (int c = 0; c < 8; ++c) {
        kv[c] = *(const bf16x8*)(kp + c * 8);
        qv[c] = *(const bf16x8*)(qp + c * 8);
    }
    float nx = xyz[(size_t)kr * 3 + 0];
    float ny = xyz[(size_t)kr * 3 + 1];
    float nz = xyz[(size_t)kr * 3 + 2];
    __builtin_amdgcn_sched_barrier(0);   // loads stay above, uses below

    float acc = 0.f;
    #pragma unroll
    for (int c = 0; c < 8; ++c) acc = dot8(kv[c], qv[c], acc);
    float lg = acc * 0.125f;                             // scale = dh^-0.5

    // --- softmax over 32-lane group (xor offsets < 32 stay in group) ---
    float mx = lg;
    #pragma unroll
    for (int off = 16; off; off >>= 1) mx = fmaxf(mx, __shfl_xor(mx, off, 64));
    float e = expf(lg - mx);
    float sum = e;
    #pragma unroll
    for (int off = 16; off; off >>= 1) sum += __shfl_xor(sum, off, 64);
    float a = e / sum;
    a_s[h][j] = a;
    if (wave == 0 && hh == 0) grow_s[j] = kr;

    // --- attn * disp max (per head, over 32 neighbors) ---
    float qx = xyz[(size_t)qrow * 3 + 0];
    float qy = xyz[(size_t)qrow * 3 + 1];
    float qz = xyz[(size_t)qrow * 3 + 2];
    float tx = a * (nx - qx);
    float ty = a * (ny - qy);
    float tz = a * (nz - qz);
    #pragma unroll
    for (int off = 16; off; off >>= 1) {
        tx = fmaxf(tx, __shfl_xor(tx, off, 64));
        ty = fmaxf(ty, __shfl_xor(ty, off, 64));
        tz = fmaxf(tz, __shfl_xor(tz, off, 64));
    }
    if (j == 0) { da_s[h][0] = tx; da_s[h][1] = ty; da_s[h][2] = tz; }

    __syncthreads();

    // --- Phase C: batch-issue ALL 32 V loads, fence, then accumulate.
    // lane -> (hh, dim pair dd, dd+1) ---
    int dd = (lane & 31) * 2;
    const u16* vbase = qkv + 1024 + h * 64 + dd;
    int rows[32];
    #pragma unroll
    for (int t = 0; t < 32; ++t) rows[t] = grow_s[t];    // fast LDS reads
    unsigned vv[32];
    #pragma unroll
    for (int t = 0; t < 32; ++t)
        vv[t] = *(const unsigned*)(vbase + (size_t)rows[t] * 1536);
    __builtin_amdgcn_sched_barrier(0);   // all 32 loads issued before any use

    float o0 = 0.f, o1 = 0.f;
    #pragma unroll
    for (int t = 0; t < 32; ++t) {
        float at = a_s[h][t];
        o0 += at * bflo(vv[t]);
        o1 += at * bfhi(vv[t]);
    }
    float dax = da_s[h][0], day = da_s[h][1], daz = da_s[h][2];
    float sp0 = dax * wsp[dd]     + day * wsp[64 + dd]     + daz * wsp[128 + dd];
    float sp1 = dax * wsp[dd + 1] + day * wsp[64 + dd + 1] + daz * wsp[128 + dd + 1];

    u16* op = fres + (size_t)qrow * INNER_ + h * 64 + dd;
    unsigned outw = (unsigned)f2bf(o0 + sp0) | ((unsigned)f2bf(o1 + sp1) << 16);
    *(unsigned*)op = outw;
}

// ---------------------------------------------------------------------------
extern "C" void kernel_launch(void* const* d_in, const int* in_sizes, int n_in,
                              void* d_out, int out_size, void* d_ws, size_t ws_size,
                              hipStream_t stream) {
    const float* xyz   = (const float*)d_in[0];   // (2,4,1024,3)
    const float* feat  = (const float*)d_in[1];   // (2,4,1024,512)
    const float* gamma = (const float*)d_in[2];   // (512)
    const float* beta  = (const float*)d_in[3];   // (512)
    const float* wqkv  = (const float*)d_in[4];   // (512,1536)
    const float* wsp   = (const float*)d_in[5];   // (3,64)
    const float* wout  = (const float*)d_in[6];   // (512,512)
    const float* bout  = (const float*)d_in[7];   // (512)
    float* out = (float*)d_out;

    char* ws = (char*)d_ws;
    u16* normf = (u16*)ws;                 ws += (size_t)ROWS_ * DIM_ * 2;        // 8 MB
    u16* wqkvT = (u16*)ws;                 ws += (size_t)3 * INNER_ * DIM_ * 2;   // 1.5 MB
    u16* woutT = (u16*)ws;                 ws += (size_t)DIM_ * INNER_ * 2;       // 0.5 MB
    u16* qkv   = (u16*)ws;                 ws += (size_t)ROWS_ * 3 * INNER_ * 2;  // 24 MB
    int* idxt  = (int*)ws;                 ws += (size_t)L_ * NFR_ * N_ * NS_ * 4;// 1 MB
    u16* fres  = normf;   // alias: normf is dead after GEMM1 completes

    transpose_cvt<<<256, 256, 0, stream>>>(wqkv, wout, wqkvT, woutT);
    ln_kernel<<<ROWS_, 256, 0, stream>>>(feat, gamma, beta, normf);
    // qkv = normf @ w_qkv : M=8192, N=1536, K=512
    gemm_bt<<<64 * 12, 256, 0, stream>>>(normf, wqkvT, qkv, nullptr,
                                         ROWS_, 3 * INNER_, DIM_, 12, 0, nullptr, nullptr);
    ballq_kernel<<<8 * 256, 256, 0, stream>>>(xyz, idxt);
    attn_kernel<<<ROWS_, 256, 0, stream>>>(xyz, qkv, idxt, wsp, fres);
    // out = gelu(fres @ w_out + b_out) + feature : M=8192, N=512, K=512
    gemm_bt<<<64 * 4, 256, 0, stream>>>(fres, woutT, nullptr, out,
                                        ROWS_, DIM_, INNER_, 4, 1, bout, feat);
}